// Round 2
// baseline (378.646 us; speedup 1.0000x reference)
//
#include <hip/hip_runtime.h>

// Problem constants (fixed by setup_inputs): B=64, T=1024, V=128, S=256
constexpr int B_ = 64;
constexpr int T_ = 1024;
constexpr int V_ = 128;
constexpr int S_ = 256;
constexpr int L2_ = 2 * S_ + 1;   // 513 extended-label positions
constexpr int NTH = 576;          // 9 waves; 513 active threads
constexpr float NEGF = -1e30f;
constexpr float INV_LN2 = 1.4426950408889634f;
constexpr float LN2 = 0.6931471805599453f;

// logaddexp in log2 domain
__device__ __forceinline__ float lae2(float a, float b) {
    float m = fmaxf(a, b);
    return m + __builtin_log2f(__builtin_exp2f(a - m) + __builtin_exp2f(b - m));
}

__global__ __launch_bounds__(NTH) void ctc_alpha_kernel(
    const float* __restrict__ lp,      // [B,T,V] natural-log softmax
    const int* __restrict__ in_len,    // [B]
    const int* __restrict__ tgt,       // [B,S]
    const int* __restrict__ tgt_len,   // [B]
    float* __restrict__ ws)            // [B] per-batch loss / max(L,1)
{
    const int b = blockIdx.x;
    const int s = threadIdx.x;
    const bool active = s < L2_;

    // double-buffered alpha, 2-element NEG pad at the front so s-1/s-2 reads
    // need no branches. All values kept in log2 domain.
    __shared__ float buf[2][L2_ + 2];

    const int L = tgt_len[b];
    const int Tb = in_len[b];

    // extended label for this position: blank (0) at even s, tgt[(s-1)/2] at odd s
    int lab = 0;
    bool skip = false;
    if (active && (s & 1)) {
        int j = s >> 1;
        lab = tgt[b * S_ + j];
        if (s >= 3) skip = (lab != tgt[b * S_ + j - 1]);
    }
    const bool valid = active && (s < 2 * L + 1);

    const float* lpb = lp + (size_t)b * T_ * V_;

    // init: pad and t=0 alpha in buf[0], NEG in buf[1]
    if (s < 2) { buf[0][s] = NEGF; buf[1][s] = NEGF; }
    if (active) {
        float a0 = NEGF;
        if (s == 0) a0 = lpb[0] * INV_LN2;
        else if (s == 1 && L > 0) a0 = lpb[lab] * INV_LN2;
        if (!valid) a0 = NEGF;
        buf[0][2 + s] = a0;
        buf[1][2 + s] = NEGF;
    }

    // prefetch lp for t=1
    float lpn = 0.0f;
    if (active) lpn = lpb[V_ + lab];

    const int wlo = s & ~63;       // wave-uniform: first position of this wave
    const int whi = wlo + 63;

    int cur = 0;
    for (int t = 1; t < Tb; ++t) {
        const float lpt = lpn * INV_LN2;
        if (active && (t + 1) < Tb) lpn = lpb[(size_t)(t + 1) * V_ + lab];

        __syncthreads();   // writes of step t-1 visible; reads of t-1 done before overwrite

        // wave-uniform band skipping:
        //  forward:  all positions of this wave unreachable yet (alpha == NEG)
        //  backward: no position of this wave can still reach the final states
        bool wave_do = (wlo <= 2 * t + 1) &&
                       (whi + 2 * (Tb - 1 - t) >= 2 * L - 1);
        if (wave_do && active) {
            float a0 = buf[cur][2 + s];
            float a1 = buf[cur][1 + s];
            float a2 = skip ? buf[cur][s] : NEGF;
            float m = fmaxf(fmaxf(a0, a1), a2);
            float r = m + __builtin_log2f(__builtin_exp2f(a0 - m) +
                                          __builtin_exp2f(a1 - m) +
                                          __builtin_exp2f(a2 - m));
            buf[cur ^ 1][2 + s] = valid ? (r + lpt) : NEGF;
        }
        cur ^= 1;
    }

    __syncthreads();
    if (s == 0) {
        float ab = buf[cur][2 + 2 * L];
        float al = (L > 0) ? buf[cur][2 + 2 * L - 1] : NEGF;
        float ll2 = lae2(ab, al);
        float loss = -ll2 * LN2;             // back to natural log
        if (loss > 1e29f) loss = 0.0f;       // zero_infinity
        ws[b] = loss / (float)(L > 0 ? L : 1);
    }
}

__global__ void ctc_reduce_kernel(const float* __restrict__ ws, float* __restrict__ out) {
    float v = ws[threadIdx.x];               // 64 threads, one wave
    #pragma unroll
    for (int o = 32; o > 0; o >>= 1) v += __shfl_down(v, o);
    if (threadIdx.x == 0) out[0] = v / (float)B_;
}

extern "C" void kernel_launch(void* const* d_in, const int* in_sizes, int n_in,
                              void* d_out, int out_size, void* d_ws, size_t ws_size,
                              hipStream_t stream) {
    const float* lp      = (const float*)d_in[0];
    const int*   in_len  = (const int*)d_in[1];
    const int*   tgt     = (const int*)d_in[2];
    const int*   tgt_len = (const int*)d_in[3];
    float* ws  = (float*)d_ws;
    float* out = (float*)d_out;

    ctc_alpha_kernel<<<B_, NTH, 0, stream>>>(lp, in_len, tgt, tgt_len, ws);
    ctc_reduce_kernel<<<1, 64, 0, stream>>>(ws, out);
}